// Round 9
// baseline (924.732 us; speedup 1.0000x reference)
//
#include <hip/hip_runtime.h>
#include <hip/hip_bf16.h>

// VQ-VAE vector quantizer forward, MI355X.
// inputs:  d_in[0] = inputs  [128*512*256] f32  (N=65536 tokens x D=256)
//          d_in[1] = embedding [1024*256] f32   (K=1024 codes x D=256)
// outputs (concat f32): [0] vq_loss | [1..16777216] quantized_st |
//          [16777217] perplexity | [16777218..] encodings one-hot [65536*1024]
//
// Distance argmin via split-bf16 MFMA (dot = xh*eh + xl*eh + xh*el) with
// best/second tracking; tokens with margin < 0.25 are recomputed exactly in
// f32 by fixup_kernel, so the final argmin equals the f32 reference argmin
// including first-min tie-break.
//
// Scratch plan: primary = d_ws at 64B-aligned offsets past the proven 270 KB
// layout (total ~1.51 MB). Fallback (small ws_size) = carve from d_out tails
// (enc tail: ehf/elf; q tail: fixup_list), which are overwritten by
// output_kernel after all readers finish (same-stream ordering).

constexpr int NTOK = 65536;
constexpr int D    = 256;
constexpr int K    = 1024;

typedef __attribute__((ext_vector_type(8))) short short8v;  // 8 bf16 = 4 VGPR
typedef __attribute__((ext_vector_type(4))) float f32x4;

#define MFMA_B16(a, b, c) __builtin_amdgcn_mfma_f32_16x16x32_bf16(a, b, c, 0, 0, 0)

static __device__ __forceinline__ void bf16split(float f, short& h, short& l) {
  __hip_bfloat16 bh = __float2bfloat16(f);
  float fh = __bfloat162float(bh);
  __hip_bfloat16 bl = __float2bfloat16(f - fh);
  h = __builtin_bit_cast(short, bh);
  l = __builtin_bit_cast(short, bl);
}

// ---------------- kernel 0: split e -> (ehf, elf) frag-linear + ||e||^2 ----
// frag-linear: element (code c, dim d) with tile=c>>4, cc=c&15, ks=d>>5,
// g=(d>>3)&3, j=d&7 stored at [((tile*8+ks)*64 + g*16+cc)*8 + j] so a wave's
// B-frag load (lane = g*16+cc) is one contiguous coalesced 1KB dwordx4.
__global__ __launch_bounds__(256) void prep_kernel(
    const float* __restrict__ emb, short* __restrict__ ehf,
    short* __restrict__ elf, float* __restrict__ e2n) {
  const int c    = (int)blockIdx.x * 256 + (int)threadIdx.x;  // grid=4 -> 0..1023
  const int tile = c >> 4, cc = c & 15;
  const float* er = emb + (size_t)c * 256;
  float s = 0.f;
  #pragma unroll
  for (int ks = 0; ks < 8; ++ks) {
    #pragma unroll
    for (int g = 0; g < 4; ++g) {
      short8v hv, lv;
      #pragma unroll
      for (int j = 0; j < 8; ++j) {
        float f = er[ks * 32 + g * 8 + j];
        s = fmaf(f, f, s);
        short h, l;
        bf16split(f, h, l);
        hv[j] = h;
        lv[j] = l;
      }
      const size_t off = ((size_t)(tile * 8 + ks) * 64 + g * 16 + cc) * 8;
      *reinterpret_cast<short8v*>(ehf + off) = hv;
      *reinterpret_cast<short8v*>(elf + off) = lv;
    }
  }
  e2n[c] = s;
}

// ---------------- kernel 1: MFMA distance + argmin + margin detect ----------
// 1 wave per 32 tokens (2 A-tiles of 16x32), 2048 waves total = full device
// residency at 2 waves/SIMD. No LDS, no barriers. B-frags stream from the
// L2-resident frag-linear eh/el. A-frag mapping: lane holds row=lane&15,
// k=(lane>>4)*8+j; C/D: col(code)=lane&15, row(token)=(lane>>4)*4+i (m89).
__global__ __launch_bounds__(256, 2) void argmin_kernel(
    const float* __restrict__ x, const short* __restrict__ ehf,
    const short* __restrict__ elf, const float* __restrict__ e2n,
    int* __restrict__ out_idx, int* __restrict__ fixup_cnt,
    int* __restrict__ fixup_list) {
  const int lane = (int)threadIdx.x & 63;
  const int wid  = (int)blockIdx.x * 4 + ((int)threadIdx.x >> 6);
  const int tok0 = wid * 32;
  const int row  = lane & 15;
  const int kgrp = lane >> 4;

  // ---- load + split this wave's 32 token rows into A-frags (in VGPRs) ----
  short8v xh0[8], xl0[8], xh1[8], xl1[8];
  {
    const float* xr0 = x + (size_t)(tok0 + row) * 256 + kgrp * 8;
    const float* xr1 = xr0 + 16 * 256;
    #pragma unroll
    for (int ks = 0; ks < 8; ++ks) {
      float4 u0 = *reinterpret_cast<const float4*>(xr0 + ks * 32);
      float4 u1 = *reinterpret_cast<const float4*>(xr0 + ks * 32 + 4);
      float4 v0 = *reinterpret_cast<const float4*>(xr1 + ks * 32);
      float4 v1 = *reinterpret_cast<const float4*>(xr1 + ks * 32 + 4);
      const float uf[8] = {u0.x, u0.y, u0.z, u0.w, u1.x, u1.y, u1.z, u1.w};
      const float vf[8] = {v0.x, v0.y, v0.z, v0.w, v1.x, v1.y, v1.z, v1.w};
      #pragma unroll
      for (int j = 0; j < 8; ++j) {
        short h, l;
        bf16split(uf[j], h, l);
        xh0[ks][j] = h; xl0[ks][j] = l;
        bf16split(vf[j], h, l);
        xh1[ks][j] = h; xl1[ks][j] = l;
      }
    }
  }

  float best[8], second[8];
  int   bidx[8];
  #pragma unroll
  for (int s = 0; s < 8; ++s) { best[s] = 3.4e38f; second[s] = 3.4e38f; bidx[s] = 0; }

  const short8v* ehv = reinterpret_cast<const short8v*>(ehf);
  const short8v* elv = reinterpret_cast<const short8v*>(elf);

  for (int tile = 0; tile < 64; ++tile) {
    f32x4 a0 = {0.f, 0.f, 0.f, 0.f}, a1 = a0, a2 = a0;
    f32x4 b0 = a0, b1 = a0, b2 = a0;
    const short8v* ep = ehv + (size_t)tile * 512 + lane;
    const short8v* lp = elv + (size_t)tile * 512 + lane;
    #pragma unroll
    for (int ks = 0; ks < 8; ++ks) {
      short8v eh = ep[ks * 64];
      short8v el = lp[ks * 64];
      a0 = MFMA_B16(xh0[ks], eh, a0);
      b0 = MFMA_B16(xh1[ks], eh, b0);
      a1 = MFMA_B16(xl0[ks], eh, a1);
      b1 = MFMA_B16(xl1[ks], eh, b1);
      a2 = MFMA_B16(xh0[ks], el, a2);
      b2 = MFMA_B16(xh1[ks], el, b2);
    }
    const int   code = tile * 16 + (lane & 15);
    const float e2v  = e2n[code];
    #pragma unroll
    for (int i = 0; i < 4; ++i) {
      {
        const float d = fmaf(-2.f, (a0[i] + a1[i]) + a2[i], e2v);
        if (d < best[i]) { second[i] = best[i]; best[i] = d; bidx[i] = code; }
        else if (d < second[i]) second[i] = d;
      }
      {
        const float d = fmaf(-2.f, (b0[i] + b1[i]) + b2[i], e2v);
        if (d < best[4 + i]) { second[4 + i] = best[4 + i]; best[4 + i] = d; bidx[4 + i] = code; }
        else if (d < second[4 + i]) second[4 + i] = d;
      }
    }
  }

  // cross-lane merge over the 16 lanes sharing kgrp (code axis).
  #pragma unroll
  for (int m = 1; m < 16; m <<= 1) {
    #pragma unroll
    for (int s = 0; s < 8; ++s) {
      const float ob = __shfl_xor(best[s], m);
      const float os = __shfl_xor(second[s], m);
      const int   oi = __shfl_xor(bidx[s], m);
      const float nsec = fminf(fmaxf(best[s], ob), fminf(second[s], os));
      if (ob < best[s] || (ob == best[s] && oi < bidx[s])) {
        best[s] = ob;
        bidx[s] = oi;
      }
      second[s] = nsec;
    }
  }
  if ((lane & 15) == 0) {
    #pragma unroll
    for (int s = 0; s < 8; ++s) {
      const int token = tok0 + (s >> 2) * 16 + kgrp * 4 + (s & 3);
      out_idx[token] = bidx[s];
      if (second[s] - best[s] < 0.25f) {  // bf16-split error bound << 0.25
        int p = atomicAdd(fixup_cnt, 1);
        if (p < NTOK) fixup_list[p] = token;
      }
    }
  }
}

// ---------------- kernel 1b: exact f32 recompute for near-tie tokens --------
__global__ __launch_bounds__(256) void fixup_kernel(
    const float* __restrict__ x, const float* __restrict__ emb,
    const float* __restrict__ e2n, const int* __restrict__ fixup_cnt,
    const int* __restrict__ fixup_list, int* __restrict__ out_idx) {
  const int lane   = (int)threadIdx.x & 63;
  const int gw     = (int)blockIdx.x * 4 + ((int)threadIdx.x >> 6);
  const int nwaves = (int)gridDim.x * 4;
  int n = *fixup_cnt;
  if (n > NTOK) n = NTOK;
  for (int fi = gw; fi < n; fi += nwaves) {
    const int token = fixup_list[fi];
    if ((unsigned)token >= (unsigned)NTOK) continue;  // defensive
    const float4* xr = reinterpret_cast<const float4*>(x + (size_t)token * 256);
    float bv = 3.4e38f;
    int   bi = 0;
    for (int ci = 0; ci < 16; ++ci) {
      const int c = ci * 64 + lane;
      const float4* er = reinterpret_cast<const float4*>(emb + (size_t)c * 256);
      float s0 = 0.f, s1 = 0.f, s2 = 0.f, s3 = 0.f;
      #pragma unroll 8
      for (int q = 0; q < 64; ++q) {
        float4 xv = xr[q], ev = er[q];
        s0 = fmaf(xv.x, ev.x, s0);
        s1 = fmaf(xv.y, ev.y, s1);
        s2 = fmaf(xv.z, ev.z, s2);
        s3 = fmaf(xv.w, ev.w, s3);
      }
      const float dist = fmaf(-2.f, (s0 + s1) + (s2 + s3), e2n[c]);
      if (dist < bv) { bv = dist; bi = c; }
    }
    #pragma unroll
    for (int m = 1; m < 64; m <<= 1) {
      const float ob = __shfl_xor(bv, m);
      const int   oi = __shfl_xor(bi, m);
      if (ob < bv || (ob == bv && oi < bi)) { bv = ob; bi = oi; }
    }
    if (lane == 0) out_idx[token] = bi;
  }
}

// ---------------- kernel 2: gather + one-hot + loss partials + histogram ----
__global__ __launch_bounds__(256) void output_kernel(
    const float* __restrict__ x, const float* __restrict__ emb,
    const int* __restrict__ idx, float* __restrict__ qout,
    float* __restrict__ enc, int* __restrict__ hist,
    double* __restrict__ lossacc) {
  const int lane = threadIdx.x & 63;
  const int gw   = (int)((blockIdx.x * 256 + threadIdx.x) >> 6);  // 0..32767
  float lsum = 0.f;
  for (int tok = gw; tok < NTOK; tok += 32768) {
    const int ki = idx[tok];
    float4 xv = reinterpret_cast<const float4*>(x + (size_t)tok * D)[lane];
    float4 ev = reinterpret_cast<const float4*>(emb + (size_t)ki * D)[lane];
    float dx = ev.x - xv.x, dy = ev.y - xv.y, dz = ev.z - xv.z,
          dw = ev.w - xv.w;
    float4 q;
    q.x = xv.x + dx; q.y = xv.y + dy; q.z = xv.z + dz; q.w = xv.w + dw;
    reinterpret_cast<float4*>(qout + (size_t)tok * D)[lane] = q;
    lsum += dx * dx + dy * dy + dz * dz + dw * dw;
    float4* erow = reinterpret_cast<float4*>(enc + (size_t)tok * K);
    #pragma unroll
    for (int r = 0; r < 4; ++r) {
      const int fi = r * 64 + lane;
      float4 z;
      z.x = (fi * 4 + 0 == ki) ? 1.f : 0.f;
      z.y = (fi * 4 + 1 == ki) ? 1.f : 0.f;
      z.z = (fi * 4 + 2 == ki) ? 1.f : 0.f;
      z.w = (fi * 4 + 3 == ki) ? 1.f : 0.f;
      erow[fi] = z;
    }
    if (lane == 0) atomicAdd(&hist[ki], 1);
  }
  #pragma unroll
  for (int m = 1; m < 64; m <<= 1) lsum += __shfl_xor(lsum, m);
  __shared__ float wsum[4];
  if (lane == 0) wsum[threadIdx.x >> 6] = lsum;
  __syncthreads();
  if (threadIdx.x == 0) {
    double tt = (double)wsum[0] + (double)wsum[1] + (double)wsum[2] +
                (double)wsum[3];
    atomicAdd(lossacc, tt);
  }
}

// ---------------- kernel 3: finalize scalars ----------------
__global__ __launch_bounds__(256) void finalize_kernel(
    const int* __restrict__ hist, const double* __restrict__ lossacc,
    float* __restrict__ out_loss, float* __restrict__ out_perp) {
  const int lane = threadIdx.x & 63;
  float part = 0.f;
  for (int k = threadIdx.x; k < K; k += 256) {
    float p = (float)hist[k] * (1.0f / 65536.0f);
    part += p * logf(p + 1e-10f);
  }
  #pragma unroll
  for (int m = 1; m < 64; m <<= 1) part += __shfl_xor(part, m);
  __shared__ float wsum[4];
  if (lane == 0) wsum[threadIdx.x >> 6] = part;
  __syncthreads();
  if (threadIdx.x == 0) {
    float ent = wsum[0] + wsum[1] + wsum[2] + wsum[3];
    out_loss[0] = 0.25f * (float)(lossacc[0] * (1.0 / 16777216.0));
    out_perp[0] = expf(-ent);
  }
}

extern "C" void kernel_launch(void* const* d_in, const int* in_sizes, int n_in,
                              void* d_out, int out_size, void* d_ws,
                              size_t ws_size, hipStream_t stream) {
  const float* x   = (const float*)d_in[0];
  const float* emb = (const float*)d_in[1];
  float* out       = (float*)d_out;

  float* loss_out = out;                        // [0]
  float* q_out    = out + 1;                    // 16777216 elements
  float* perp_out = out + 1 + (size_t)NTOK * D; // [16777217]
  float* enc_out  = perp_out + 1;               // 67108864 elements

  // --- workspace (270 KB base, round-4/5-proven footprint) ---
  char*   wsb  = (char*)d_ws;
  int*    idx  = (int*)wsb;                     // 262144 B @ 0
  float*  e2n  = (float*)(wsb + 262144);        //   4096 B @ 262144
  int*    hist = (int*)(wsb + 266240);          //   4096 B @ 266240
  double* acc  = (double*)(wsb + 270336);       //      8 B @ 270336
  int*    fcnt = (int*)(wsb + 270344);          //      4 B @ 270344

  // --- split-bf16 scratch: prefer d_ws (64B-aligned, +1.31 MB); fall back to
  //     d_out tails (overwritten by output_kernel after readers finish).
  //     Deterministic host-side choice -> graph-capture safe. ---
  short* ehf;
  short* elf;
  int*   flist;
  if (ws_size >= (size_t)270400 + 524288 * 2 + 262144) {
    ehf   = (short*)(wsb + 270400);            // 524288 B
    elf   = (short*)(wsb + 270400 + 524288);   // 524288 B
    flist = (int*)(wsb + 270400 + 1048576);    // 262144 B
  } else {
    ehf   = (short*)(enc_out + (size_t)67108864 - 262144);  // 1 MB enc tail
    elf   = (short*)(enc_out + (size_t)67108864 - 131072);
    flist = (int*)(q_out + (size_t)16777216 - 65536);       // 256 KB q tail
  }

  // zero hist + loss acc + fixup count (ws is poisoned 0xAA before each call)
  hipMemsetAsync(wsb + 266240, 0, 8192, stream);

  prep_kernel<<<4, 256, 0, stream>>>(emb, ehf, elf, e2n);
  argmin_kernel<<<512, 256, 0, stream>>>(x, ehf, elf, e2n, idx, fcnt, flist);
  fixup_kernel<<<512, 256, 0, stream>>>(x, emb, e2n, fcnt, flist, idx);
  output_kernel<<<8192, 256, 0, stream>>>(x, emb, idx, q_out, enc_out, hist,
                                          acc);
  finalize_kernel<<<1, 256, 0, stream>>>(hist, acc, loss_out, perp_out);
}